// Round 6
// baseline (124.370 us; speedup 1.0000x reference)
//
#include <hip/hip_runtime.h>

// log2-domain "log 0": exp2(-30000) == 0, exactly representable in half, never NaN.
#define NEG2 (-30000.0f)
#define L2E  1.4426950408889634f
#define LN2  0.6931471805599453f

constexpr int B = 8, T = 128, U = 64, U1 = 65, V = 512;

// ws layout in HALVES: exp(trans-mt) f16 rows, then exp(pred-mp) f16 rows
constexpr size_t ETH_TOT = (size_t)B * T * V;     // 524288 halves
typedef _Float16 half_t;
typedef _Float16 v4h __attribute__((ext_vector_type(4)));
typedef _Float16 v8h __attribute__((ext_vector_type(8)));
typedef float    v4f __attribute__((ext_vector_type(4)));

__device__ __forceinline__ float wave_shr1(float x) {  // lane i <- lane i-1 (lane0 keeps own)
    int v = __float_as_int(x);
    int r = __builtin_amdgcn_update_dpp(v, v, 0x138, 0xF, 0xF, false); // wave_shr:1
    return __int_as_float(r);
}

__device__ __forceinline__ float dp_step(float cur, uint w, float a00, int d, int l, int tl) {
    const int t = d - l - 1;
    union { uint u; half_t h[2]; } cv; cv.u = w;
    const float bn = (float)cv.h[0];       // blank~[t-1][u]
    const float lb = (float)cv.h[1];       // lab~[t][u-1]
    const float sh = wave_shr1(cur);
    const float lv = (l == 0) ? a00 : sh;  // alpha[t][u-1]
    const float a2 = lv + lb;
    const float a1 = (t >= 1) ? cur + bn : NEG2;
    const float m  = fmaxf(a1, a2);
    const float nc = m + __log2f(exp2f(a1 - m) + exp2f(a2 - m));
    return ((t >= 0) && (t <= tl)) ? nc : cur;
}

// One block per batch element: prep -> joint(MFMA, epilogue straight to LDS) -> DP.
__global__ __launch_bounds__(512) void k_fused(const float* __restrict__ trans,
                                               const float* __restrict__ pred,
                                               const int* __restrict__ labels,
                                               const int* __restrict__ act_lens,
                                               const int* __restrict__ label_lens,
                                               float* __restrict__ ws,
                                               float* __restrict__ out) {
    const int b   = blockIdx.x;
    const int tid = threadIdx.x;
    const int wid = tid >> 6;      // 0..7
    const int l   = tid & 63;

    __shared__ uint   Pds[192 * 64];   // 48 KB diag lattice: row r=d-1; x=blank~[r-c-1][c+1], y=lab~[r-c][c]
    __shared__ float  af[T];           // alpha~[t][0]
    __shared__ float  C0[T];           // blank~[t][0]
    __shared__ float  MT[T], T0[T];
    __shared__ float  MP[U1], P0[U1], PL[U1];
    __shared__ half_t TL[T * 64];      // trans[t][labels[u]] 16 KB

    half_t* wsh  = (half_t*)ws;
    half_t* ethb = wsh + (size_t)b * T * V;             // this b's exp(trans) f16 rows
    half_t* ephb = wsh + ETH_TOT + (size_t)b * U1 * V;  // this b's exp(pred) f16 rows

    const int ul = label_lens[b];          // in [32,64]
    const int tl = act_lens[b] - 1;        // >= 63
    const int mylbl = labels[b * U + l];   // lane == u

    // ---- phase 1: row max + exp (f16) + gather precomputes ----
    for (int r = wid; r < T + U1; r += 8) {
        const float* src; half_t* dst;
        if (r < T) { src = trans + ((size_t)b * T + r) * V;        dst = ethb + (size_t)r * V; }
        else       { src = pred  + ((size_t)b * U1 + (r - T)) * V; dst = ephb + (size_t)(r - T) * V; }

        const float4 a = ((const float4*)src)[l];
        const float4 c = ((const float4*)src)[l + 64];
        float m = fmaxf(fmaxf(fmaxf(a.x, a.y), fmaxf(a.z, a.w)),
                        fmaxf(fmaxf(c.x, c.y), fmaxf(c.z, c.w)));
        #pragma unroll
        for (int off = 32; off >= 1; off >>= 1) m = fmaxf(m, __shfl_xor(m, off));

        v4h h0 = { (half_t)__expf(a.x - m), (half_t)__expf(a.y - m),
                   (half_t)__expf(a.z - m), (half_t)__expf(a.w - m) };
        v4h h1 = { (half_t)__expf(c.x - m), (half_t)__expf(c.y - m),
                   (half_t)__expf(c.z - m), (half_t)__expf(c.w - m) };
        ((v4h*)dst)[l]      = h0;
        ((v4h*)dst)[l + 64] = h1;

        if (r < T) {
            TL[r * 64 + l] = (half_t)src[mylbl];
            if (l == 0) { MT[r] = m; T0[r] = a.x; }
        } else {
            const int u = r - T;
            if (l == 0) {
                MP[u] = m; P0[u] = a.x;
                if (u < U) PL[u] = src[labels[b * U + u]];
            }
        }
    }
    __threadfence_block();
    __syncthreads();

    // ---- phase 2: MFMA joint GEMM, wave wid = t-tile, 5 u-tiles; epilogue -> LDS ----
    {
        const int n = l & 15, q = l >> 4;
        const int t0 = wid * 16;
        const v8h* A = (const v8h*)(ethb + (size_t)(t0 + n) * V);
        #pragma unroll 1
        for (int ut = 0; ut < 5; ++ut) {
            const int u0 = ut * 16;
            const int uc = (u0 + n <= 64) ? (u0 + n) : 64;
            const v8h* Bp = (const v8h*)(ephb + (size_t)uc * V);

            v4f acc = {0.f, 0.f, 0.f, 0.f};
            #pragma unroll
            for (int c = 0; c < 64; c += 4)        // 16 MFMAs, K=512
                acc = __builtin_amdgcn_mfma_f32_16x16x32_f16(A[c + q], Bp[c + q], acc, 0, 0, 0);

            const int u = u0 + n;                  // C/D: col=lane&15 -> u, row=q*4+i -> t
            if (u > 64) continue;
            const float mp_u = MP[u], pr0 = P0[u];
            const bool has_lab = (u < 64);
            const float prl = has_lab ? PL[u] : 0.f;
            #pragma unroll
            for (int i = 0; i < 4; ++i) {
                const int t = t0 + q * 4 + i;
                const float lse2 = (MT[t] + mp_u) * L2E + __log2f(acc[i]);
                const float bl2 = (T0[t] + pr0) * L2E - lse2;     // blank~[t][u]
                const int row = t + u;                            // = d-1
                if (u >= 1) ((half_t*)&Pds[row * 64 + (u - 1)])[0] = (half_t)bl2;
                else        C0[t] = bl2;
                if (has_lab) {
                    const float lb2 = (u >= ul) ? NEG2
                                     : ((float)TL[t * 64 + u] + prl) * L2E - lse2;  // lab~[t][u]
                    ((half_t*)&Pds[row * 64 + u])[1] = (half_t)lb2;
                }
            }
        }
    }
    __syncthreads();

    // ---- phase 3: anti-diagonal DP, wave 0 only ----
    if (wid != 0) return;

    // alpha0 column: inclusive prefix scan of C0 (within-wave; LDS ordering via lgkmcnt)
    float x0 = C0[l], x1 = C0[64 + l];
    #pragma unroll
    for (int off = 1; off < 64; off <<= 1) { float y = __shfl_up(x0, off); if (l >= off) x0 += y; }
    #pragma unroll
    for (int off = 1; off < 64; off <<= 1) { float y = __shfl_up(x1, off); if (l >= off) x1 += y; }
    const float tot = __shfl(x0, 63);
    if (l == 0) af[0] = 0.0f;
    af[l + 1] = x0;                        // t = 1..64
    if (l < 63) af[65 + l] = tot + x1;     // t = 65..127

    const int dmax = tl + ul;              // <= 191
    const int steps = (dmax + 3) >> 2;     // overshoot steps are no-ops (t>tl guard)

    uint  w0 = Pds[0 * 64 + l], w1 = Pds[1 * 64 + l], w2 = Pds[2 * 64 + l], w3 = Pds[3 * 64 + l];
    float a0 = af[0], a1 = af[1], a2 = af[2], a3 = af[3];

    float cur = 0.0f;                      // lane l owns u = l+1; at step d, t = d-l-1
    int d = 1;
    for (int s = 0; s < steps; ++s) {
        cur = dp_step(cur, w0, a0, d, l, tl);
        w0 = Pds[min(d + 3, 191) * 64 + l]; a0 = af[min(d + 3, T - 1)]; ++d;
        cur = dp_step(cur, w1, a1, d, l, tl);
        w1 = Pds[min(d + 3, 191) * 64 + l]; a1 = af[min(d + 3, T - 1)]; ++d;
        cur = dp_step(cur, w2, a2, d, l, tl);
        w2 = Pds[min(d + 3, 191) * 64 + l]; a2 = af[min(d + 3, T - 1)]; ++d;
        cur = dp_step(cur, w3, a3, d, l, tl);
        w3 = Pds[min(d + 3, 191) * 64 + l]; a3 = af[min(d + 3, T - 1)]; ++d;
    }

    if (l == ul - 1) {                     // cur == alpha~[tl][ul]
        union { uint u; half_t h[2]; } cv; cv.u = Pds[dmax * 64 + (ul - 1)]; // d = dmax+1
        atomicAdd(out, -((cur + (float)cv.h[0]) * LN2));
    }
}

extern "C" void kernel_launch(void* const* d_in, const int* in_sizes, int n_in,
                              void* d_out, int out_size, void* d_ws, size_t ws_size,
                              hipStream_t stream) {
    const float* trans      = (const float*)d_in[0];
    const float* pred       = (const float*)d_in[1];
    const int*   labels     = (const int*)d_in[2];
    const int*   act_lens   = (const int*)d_in[3];
    const int*   label_lens = (const int*)d_in[4];
    float* ws  = (float*)d_ws;
    float* out = (float*)d_out;

    hipMemsetAsync(out, 0, sizeof(float), stream);   // graph-capturable memset node
    k_fused<<<B, 512, 0, stream>>>(trans, pred, labels, act_lens, label_lens, ws, out);
}